// Round 1
// baseline (1468.360 us; speedup 1.0000x reference)
//
#include <hip/hip_runtime.h>
#include <hip/hip_bf16.h>
#include <cstdint>
#include <cstddef>

// ---------------------------------------------------------------------------
// DeepseekMoE: x(1,2048,2048) fp32; gate_w(16,2048); w1(16,2816,2048);
// w2(16,2048,1408); shared_w1(5632,2048); shared_w2(2048,2816). Out fp32 T x H.
// Round 3:
//  - double-buffered LDS + prefetch-before-compute, ONE barrier per K-step
//    (hides L3 latency of weight global_load_lds that the old
//    stage->sync->compute->sync structure ate every step)
//  - routed down-proj writes per-slot rows to slot_out scratch (aliased over
//    dead w1b) + combine kernel; removes 25.2M fp32 atomicAdds
//  - shared expert folded into the grouped launches as blockIdx.z == NE
//    (one block pool -> single tail, two fewer launch boundaries)
// ---------------------------------------------------------------------------

typedef __bf16 bf16;
typedef __bf16 bf16x8 __attribute__((ext_vector_type(8)));
typedef float  f32x4  __attribute__((ext_vector_type(4)));

constexpr int Hdim  = 2048;
constexpr int Idim  = 1408;
constexpr int NE    = 16;
constexpr int TOPK  = 6;
constexpr int ISdim = 2816;
constexpr int Ttok  = 2048;
constexpr int BMT   = 256;            // M tile for both grouped GEMMs
// sum over experts of ceil(cnt_e/256)*256 <= 12288 + 16*255 = 16368
constexpr int MAX_SLOTS = 16384;

__device__ __forceinline__ void gll16(const void* g, void* l) {
  __builtin_amdgcn_global_load_lds((__attribute__((address_space(1))) void*)(g),
                                   (__attribute__((address_space(3))) void*)(l),
                                   16, 0, 0);
}

// --------------------------- small kernels ---------------------------------

__global__ void init_kernel(int* cnt, int* fill, int* tok_of_slot, float* wt_of_slot) {
  int i = blockIdx.x * 256 + threadIdx.x;
  if (i < NE) { cnt[i] = 0; fill[i] = 0; }
  if (i < MAX_SLOTS) { tok_of_slot[i] = -1; wt_of_slot[i] = 0.f; }
}

// fp32 -> bf16, 8 elems/thread
__global__ void cvt_kernel(const float* __restrict__ src, bf16* __restrict__ dst, int n8) {
  int i = blockIdx.x * 256 + threadIdx.x;
  if (i >= n8) return;
  f32x4 f0 = *(const f32x4*)(src + (size_t)i * 8);
  f32x4 f1 = *(const f32x4*)(src + (size_t)i * 8 + 4);
  bf16x8 v;
#pragma unroll
  for (int j = 0; j < 4; j++) { v[j] = (bf16)f0[j]; v[j + 4] = (bf16)f1[j]; }
  *(bf16x8*)(dst + (size_t)i * 8) = v;
}

__global__ void router_kernel(const float* __restrict__ x, const float* __restrict__ gw,
                              int* __restrict__ sel_e, float* __restrict__ sel_w,
                              int* __restrict__ cnt) {
  int t = blockIdx.x;
  int lane = threadIdx.x;
  const float* xr = x + (size_t)t * Hdim;
  float acc[NE];
#pragma unroll
  for (int e = 0; e < NE; e++) acc[e] = 0.f;
  for (int h = lane; h < Hdim; h += 64) {
    float xv = xr[h];
#pragma unroll
    for (int e = 0; e < NE; e++) acc[e] += xv * gw[e * Hdim + h];
  }
#pragma unroll
  for (int e = 0; e < NE; e++) {
#pragma unroll
    for (int off = 32; off > 0; off >>= 1) acc[e] += __shfl_xor(acc[e], off, 64);
  }
  if (lane == 0) {
    float m = acc[0];
#pragma unroll
    for (int e = 1; e < NE; e++) m = fmaxf(m, acc[e]);
    float p[NE]; float s = 0.f;
#pragma unroll
    for (int e = 0; e < NE; e++) { p[e] = __expf(acc[e] - m); s += p[e]; }
    float inv = 1.f / s;
    bool used[NE];
#pragma unroll
    for (int e = 0; e < NE; e++) used[e] = false;
    for (int k = 0; k < TOPK; k++) {   // strict > keeps lowest index on ties (lax.top_k)
      int best = 0; float bv = -1.f;
      for (int e = 0; e < NE; e++) if (!used[e] && p[e] > bv) { bv = p[e]; best = e; }
      used[best] = true;
      sel_e[t * TOPK + k] = best;
      sel_w[t * TOPK + k] = bv * inv;   // NORM_TOPK_PROB=False -> raw softmax prob
      atomicAdd(&cnt[best], 1);
    }
  }
}

__global__ void scan_kernel(const int* __restrict__ cnt, int* __restrict__ pbase,
                            int* __restrict__ mtiles) {
  if (threadIdx.x == 0 && blockIdx.x == 0) {
    int pb = 0;
    for (int e = 0; e < NE; e++) {
      pbase[e] = pb;
      int mt = (cnt[e] + BMT - 1) / BMT;
      mtiles[e] = mt;
      pb += mt * BMT;
    }
  }
}

__global__ void assign_kernel(const int* __restrict__ sel_e, const float* __restrict__ sel_w,
                              const int* __restrict__ pbase, int* __restrict__ fill,
                              int* __restrict__ tok_of_slot, float* __restrict__ wt_of_slot,
                              int* __restrict__ slot_of) {
  int i = blockIdx.x * 256 + threadIdx.x;
  if (i >= Ttok * TOPK) return;
  int e = sel_e[i];
  int t = i / TOPK;
  int pos = atomicAdd(&fill[e], 1);
  int slot = pbase[e] + pos;
  tok_of_slot[slot] = t;
  wt_of_slot[slot] = sel_w[i];
  slot_of[i] = slot;
}

// --------------------------- gate+up fused GEMM -----------------------------
// act[row][col] = silu(A@G^T) * (A@U^T) * rowscale.  BN=64 per matmul, BK=32.
// blockIdx.z in [0,NE]: z<NE -> routed expert e=z (rows are slots, gathered
// tokens, scale=wt); z==NE -> shared expert (rows are tokens, scale=1).
// Double-buffered LDS; prefetch of K-step k+1 issued BEFORE compute of k;
// single __syncthreads() per K-step (its vmcnt(0) lands ~300cy after issue).

template <int BM>
__global__ __launch_bounds__(256, 2)
void gateup_kernel(const bf16* __restrict__ Abase,
                   const bf16* __restrict__ w1b, const bf16* __restrict__ sw1b,
                   bf16* __restrict__ actx, bf16* __restrict__ acts,
                   const int* __restrict__ tok_of_slot, const float* __restrict__ wt_of_slot,
                   const int* __restrict__ pbase, const int* __restrict__ mtiles) {
  constexpr int NQ = BM / 64;        // 64-row staging chunks of A
  constexpr int WROWS = BM / 4;      // rows per wave
  constexpr int NI = WROWS / 16;     // 16-row MFMA fragments per wave
  constexpr int K = Hdim;
  const int z = blockIdx.z;
  const bool SH = (z == NE);
  const bf16* Wb; bf16* C; int Isz, row0;
  if (SH) {
    Wb = sw1b; C = acts; Isz = ISdim;
    row0 = blockIdx.y * BM;
  } else {
    if (blockIdx.x >= Idim / 64) return;           // routed uses 22 of 44 col tiles
    if ((int)blockIdx.y >= mtiles[z]) return;
    Wb = w1b + (size_t)z * 2 * Idim * Hdim; C = actx; Isz = Idim;
    row0 = pbase[z] + blockIdx.y * BM;
  }
  const int col0 = blockIdx.x * 64;
  const int tid = threadIdx.x;
  const int lane = tid & 63;
  const int wv = tid >> 6;
  const int m16 = lane & 15, quad = lane >> 4;

  __shared__ __align__(16) bf16 ldsA[2][BM * 32];
  __shared__ __align__(16) bf16 ldsG[2][64 * 32];
  __shared__ __align__(16) bf16 ldsU[2][64 * 32];

  const int srow = tid >> 2;         // 0..63
  const int scol = (tid & 3) * 8;    // 0,8,16,24

  const bf16* aptr[NQ];
#pragma unroll
  for (int q = 0; q < NQ; q++) {
    int r = row0 + q * 64 + srow;
    int tok = SH ? r : tok_of_slot[r];
    if (tok < 0) tok = 0;            // pad slot: rowscale==0 zeroes its act
    aptr[q] = Abase + (size_t)tok * K + scol;
  }
  const bf16* gptr = Wb + (size_t)(col0 + srow) * K + scol;
  const bf16* uptr = Wb + (size_t)(Isz + col0 + srow) * K + scol;

  f32x4 accg[NI][4], accu[NI][4];
#pragma unroll
  for (int i = 0; i < NI; i++)
#pragma unroll
    for (int j = 0; j < 4; j++)
#pragma unroll
      for (int r = 0; r < 4; r++) { accg[i][j][r] = 0.f; accu[i][j][r] = 0.f; }

  auto stage = [&](int b, int k) {
    gll16(gptr + k, &ldsG[b][tid * 8]);
    gll16(uptr + k, &ldsU[b][tid * 8]);
#pragma unroll
    for (int q = 0; q < NQ; q++) gll16(aptr[q] + k, &ldsA[b][q * 2048 + tid * 8]);
  };

  stage(0, 0);
  __syncthreads();                    // implicit vmcnt(0): buf0 ready
  for (int k0 = 0; k0 < K; k0 += 32) {
    const int cur = (k0 >> 5) & 1;
    if (k0 + 32 < K) stage(cur ^ 1, k0 + 32);   // prefetch BEFORE compute
    bf16x8 af[NI], gf[4], uf[4];
#pragma unroll
    for (int i = 0; i < NI; i++)
      af[i] = *(const bf16x8*)(&ldsA[cur][(wv * WROWS + i * 16 + m16) * 32 + quad * 8]);
#pragma unroll
    for (int j = 0; j < 4; j++) {
      gf[j] = *(const bf16x8*)(&ldsG[cur][(j * 16 + m16) * 32 + quad * 8]);
      uf[j] = *(const bf16x8*)(&ldsU[cur][(j * 16 + m16) * 32 + quad * 8]);
    }
#pragma unroll
    for (int i = 0; i < NI; i++)
#pragma unroll
      for (int j = 0; j < 4; j++) {
        accg[i][j] = __builtin_amdgcn_mfma_f32_16x16x32_bf16(af[i], gf[j], accg[i][j], 0, 0, 0);
        accu[i][j] = __builtin_amdgcn_mfma_f32_16x16x32_bf16(af[i], uf[j], accu[i][j], 0, 0, 0);
      }
    __syncthreads();   // waits prefetch (issued ~300cy ago) + guards buffer swap
  }

#pragma unroll
  for (int i = 0; i < NI; i++) {
#pragma unroll
    for (int r = 0; r < 4; r++) {
      int grow = row0 + wv * WROWS + i * 16 + quad * 4 + r;
      float scale = SH ? 1.f : wt_of_slot[grow];
#pragma unroll
      for (int j = 0; j < 4; j++) {
        float g = accg[i][j][r];
        float u = accu[i][j][r];
        float a = g * u * scale / (1.f + __expf(-g));   // silu(g)*u*scale
        C[(size_t)grow * Isz + (col0 + j * 16 + m16)] = (bf16)a;
      }
    }
  }
}

// --------------------------- down-proj GEMM ---------------------------------
// BN=128, BK=32, double-buffered like gateup. z<NE: rows are slots of expert z,
// plain store to slot_out[slot][H] (no atomics). z==NE: shared path, plain
// store to out[token][H]. K differs per path (Idim vs ISdim).

template <int BM>
__global__ __launch_bounds__(256, 2)
void down_kernel(const bf16* __restrict__ actx, const bf16* __restrict__ acts,
                 const bf16* __restrict__ w2b, const bf16* __restrict__ sw2b,
                 float* __restrict__ slot_out, float* __restrict__ out,
                 const int* __restrict__ pbase, const int* __restrict__ mtiles) {
  constexpr int NQ = BM / 64;
  constexpr int WROWS = BM / 4;
  constexpr int NI = WROWS / 16;
  const int z = blockIdx.z;
  const bool SH = (z == NE);
  const bf16* A; const bf16* Wb; float* dst; int K, row0;
  if (SH) {
    A = acts; Wb = sw2b; dst = out; K = ISdim;
    row0 = blockIdx.y * BM;
  } else {
    if ((int)blockIdx.y >= mtiles[z]) return;
    A = actx; Wb = w2b + (size_t)z * Hdim * Idim; dst = slot_out; K = Idim;
    row0 = pbase[z] + blockIdx.y * BM;
  }
  const int col0 = blockIdx.x * 128;
  const int tid = threadIdx.x;
  const int lane = tid & 63;
  const int wv = tid >> 6;
  const int m16 = lane & 15, quad = lane >> 4;

  __shared__ __align__(16) bf16 ldsA[2][BM * 32];
  __shared__ __align__(16) bf16 ldsB[2][128 * 32];

  const int srow = tid >> 2;
  const int scol = (tid & 3) * 8;

  const bf16* aptr[NQ];
#pragma unroll
  for (int q = 0; q < NQ; q++)
    aptr[q] = A + (size_t)(row0 + q * 64 + srow) * K + scol;
  const bf16* bptr[2];
#pragma unroll
  for (int q = 0; q < 2; q++)
    bptr[q] = Wb + (size_t)(col0 + q * 64 + srow) * K + scol;

  f32x4 acc[NI][8];
#pragma unroll
  for (int i = 0; i < NI; i++)
#pragma unroll
    for (int j = 0; j < 8; j++)
#pragma unroll
      for (int r = 0; r < 4; r++) acc[i][j][r] = 0.f;

  auto stage = [&](int b, int k) {
#pragma unroll
    for (int q = 0; q < 2; q++) gll16(bptr[q] + k, &ldsB[b][q * 2048 + tid * 8]);
#pragma unroll
    for (int q = 0; q < NQ; q++) gll16(aptr[q] + k, &ldsA[b][q * 2048 + tid * 8]);
  };

  stage(0, 0);
  __syncthreads();
  for (int k0 = 0; k0 < K; k0 += 32) {
    const int cur = (k0 >> 5) & 1;
    if (k0 + 32 < K) stage(cur ^ 1, k0 + 32);
    bf16x8 af[NI], bfr[8];
#pragma unroll
    for (int i = 0; i < NI; i++)
      af[i] = *(const bf16x8*)(&ldsA[cur][(wv * WROWS + i * 16 + m16) * 32 + quad * 8]);
#pragma unroll
    for (int j = 0; j < 8; j++)
      bfr[j] = *(const bf16x8*)(&ldsB[cur][(j * 16 + m16) * 32 + quad * 8]);
#pragma unroll
    for (int i = 0; i < NI; i++)
#pragma unroll
      for (int j = 0; j < 8; j++)
        acc[i][j] = __builtin_amdgcn_mfma_f32_16x16x32_bf16(af[i], bfr[j], acc[i][j], 0, 0, 0);
    __syncthreads();
  }

#pragma unroll
  for (int i = 0; i < NI; i++) {
#pragma unroll
    for (int r = 0; r < 4; r++) {
      int grow = row0 + wv * WROWS + i * 16 + quad * 4 + r;
      float* orow = dst + (size_t)grow * Hdim;   // slot row (routed) or token row (shared)
#pragma unroll
      for (int j = 0; j < 8; j++) orow[col0 + j * 16 + m16] = acc[i][j][r];
    }
  }
}

// --------------------------- combine ----------------------------------------
// out[t] (already holds shared-path result) += sum_k slot_out[slot_of[t][k]].

__global__ void combine_kernel(const float* __restrict__ slot_out,
                               const int* __restrict__ slot_of,
                               float* __restrict__ out) {
  const int t = blockIdx.x;
  const int c = threadIdx.x * 8;
  float* op = out + (size_t)t * Hdim + c;
  f32x4 a0 = *(const f32x4*)op;
  f32x4 a1 = *(const f32x4*)(op + 4);
#pragma unroll
  for (int k = 0; k < TOPK; k++) {
    int s = slot_of[t * TOPK + k];
    const float* sp = slot_out + (size_t)s * Hdim + c;
    f32x4 b0 = *(const f32x4*)sp;
    f32x4 b1 = *(const f32x4*)(sp + 4);
    a0 += b0; a1 += b1;
  }
  *(f32x4*)op = a0;
  *(f32x4*)(op + 4) = a1;
}

// --------------------------- launch ----------------------------------------

extern "C" void kernel_launch(void* const* d_in, const int* in_sizes, int n_in,
                              void* d_out, int out_size, void* d_ws, size_t ws_size,
                              hipStream_t stream) {
  (void)in_sizes; (void)n_in; (void)out_size; (void)ws_size;
  const float* x   = (const float*)d_in[0];
  const float* gw  = (const float*)d_in[1];
  const float* w1  = (const float*)d_in[2];
  const float* w2  = (const float*)d_in[3];
  const float* sw1 = (const float*)d_in[4];
  const float* sw2 = (const float*)d_in[5];
  float* out = (float*)d_out;

  char* ws = (char*)d_ws;
  size_t off = 0;
  auto alloc = [&](size_t bytes) -> void* {
    void* p = ws + off;
    off += (bytes + 255) & ~(size_t)255;
    return p;
  };
  int*   cnt   = (int*)alloc(NE * 4);
  int*   fill  = (int*)alloc(NE * 4);
  int*   pbase = (int*)alloc(NE * 4);
  int*   mtl   = (int*)alloc(NE * 4);
  int*   sel_e = (int*)alloc((size_t)Ttok * TOPK * 4);
  float* sel_w = (float*)alloc((size_t)Ttok * TOPK * 4);
  int*   slotf = (int*)alloc((size_t)Ttok * TOPK * 4);
  int*   tok   = (int*)alloc((size_t)MAX_SLOTS * 4);
  float* wt    = (float*)alloc((size_t)MAX_SLOTS * 4);
  bf16*  xb    = (bf16*)alloc((size_t)Ttok * Hdim * 2);
  bf16*  actx  = (bf16*)alloc((size_t)MAX_SLOTS * Idim * 2);   // expert activations
  bf16*  acts  = (bf16*)alloc((size_t)Ttok * ISdim * 2);       // shared activations

  const size_t n_w1  = (size_t)NE * 2 * Idim * Hdim;   // 92.3M
  const size_t n_w2  = (size_t)NE * Hdim * Idim;       // 46.1M
  const size_t n_sw1 = (size_t)2 * ISdim * Hdim;       // 11.5M
  const size_t n_sw2 = (size_t)Hdim * ISdim;           // 5.8M
  bf16* w1b  = (bf16*)alloc(n_w1 * 2);    // 184.6 MB
  bf16* w2b  = (bf16*)alloc(n_w2 * 2);
  bf16* sw1b = (bf16*)alloc(n_sw1 * 2);
  bf16* sw2b = (bf16*)alloc(n_sw2 * 2);
  // slot_out (MAX_SLOTS x H fp32 = 134 MB) aliases w1b (184.6 MB): w1b is dead
  // once the gateup launch completes, and the down launch that writes slot_out
  // is strictly after it in-stream. Same total ws footprint as previous round.
  float* slot_out = (float*)w1b;

  init_kernel<<<(MAX_SLOTS + 255) / 256, 256, 0, stream>>>(cnt, fill, tok, wt);
  cvt_kernel<<<((int)(Ttok * (size_t)Hdim / 8) + 255) / 256, 256, 0, stream>>>(x, xb, Ttok * Hdim / 8);
  router_kernel<<<Ttok, 64, 0, stream>>>(x, gw, sel_e, sel_w, cnt);
  scan_kernel<<<1, 64, 0, stream>>>(cnt, pbase, mtl);
  assign_kernel<<<(Ttok * TOPK + 255) / 256, 256, 0, stream>>>(sel_e, sel_w, pbase, fill, tok, wt, slotf);

  cvt_kernel<<<((int)(n_w1 / 8) + 255) / 256, 256, 0, stream>>>(w1, w1b, (int)(n_w1 / 8));
  cvt_kernel<<<((int)(n_w2 / 8) + 255) / 256, 256, 0, stream>>>(w2, w2b, (int)(n_w2 / 8));
  cvt_kernel<<<((int)(n_sw1 / 8) + 255) / 256, 256, 0, stream>>>(sw1, sw1b, (int)(n_sw1 / 8));
  cvt_kernel<<<((int)(n_sw2 / 8) + 255) / 256, 256, 0, stream>>>(sw2, sw2b, (int)(n_sw2 / 8));

  // merged gateup: x = 44 col tiles (shared; routed guards to 22), y = 8 M
  // tiles (covers worst-case ceil(2048/256)=8 for any expert), z = 17.
  gateup_kernel<BMT><<<dim3(ISdim / 64, Ttok / BMT, NE + 1), 256, 0, stream>>>(
      xb, w1b, sw1b, actx, acts, tok, wt, pbase, mtl);
  // merged down: x = 16 col tiles, y = 8, z = 17.
  down_kernel<BMT><<<dim3(Hdim / 128, Ttok / BMT, NE + 1), 256, 0, stream>>>(
      actx, acts, w2b, sw2b, slot_out, out, pbase, mtl);
  combine_kernel<<<Ttok, Hdim / 8, 0, stream>>>(slot_out, slotf, out);
}